// Round 7
// baseline (140.779 us; speedup 1.0000x reference)
//
#include <hip/hip_runtime.h>

#define BB 32
#define SS 2048
#define DIN 1024
#define DST 512
#define DH 256   // DST/2
#define NST 64   // MAX_STATES
#define SC 64                 // seq rows per pool chunk
#define CHUNKS (SS / SC)      // 32
#define POOLBLKS (BB * CHUNKS)  // 1024

__device__ __forceinline__ float dot4(float4 a, float4 b) {
    return a.x * b.x + a.y * b.y + a.z * b.z + a.w * b.w;
}

__device__ __forceinline__ float wave_reduce(float d) {
    d += __shfl_xor(d, 1);
    d += __shfl_xor(d, 2);
    d += __shfl_xor(d, 4);
    d += __shfl_xor(d, 8);
    d += __shfl_xor(d, 16);
    d += __shfl_xor(d, 32);
    return d;
}

// ============ kA: imp chain (64) + pool partials (1024) + bcast (1024) ======
// blocks 0..63      : importance logit for state i=blk (hs never stored)
// blocks 64..1087   : pool partial sums, 64 seq rows each (task = blk-64)
// blocks 1088..2111 : broadcast state_bank -> allocated_states
__global__ void kA(const float* __restrict__ x,
                   const float* __restrict__ bank,
                   const float* __restrict__ Ws1, const float* __restrict__ bs1,
                   const float* __restrict__ Ws2, const float* __restrict__ bs2,
                   float* __restrict__ partial, float* __restrict__ imp,
                   float* __restrict__ out) {
    int blk = blockIdx.x;
    int t = threadIdx.x;
    if (blk >= 64 && blk < 64 + POOLBLKS) {
        int task = blk - 64;
        int b = task >> 5;        // batch
        int c = task & 31;        // chunk of 64 seq rows
        const float4* xp = (const float4*)(x + ((size_t)b * SS + (size_t)c * SC) * DIN);
        float4 acc = make_float4(0.f, 0.f, 0.f, 0.f);
#pragma unroll 8
        for (int s = 0; s < SC; ++s) {
            float4 v = xp[s * (DIN / 4) + t];
            acc.x += v.x; acc.y += v.y; acc.z += v.z; acc.w += v.w;
        }
        ((float4*)(partial + (size_t)task * DIN))[t] = acc;
    } else if (blk < 64) {
        // imp[i] = sum_j relu(dot(bank_i, Ws1_j) + bs1_j) * Ws2[j] + bs2
        int i = blk;
        int w = t >> 6, lane = t & 63;
        __shared__ float s_zp[4];
        const float4* brow = (const float4*)(bank + (size_t)i * DST);
        float4 p0 = brow[lane * 2];        // lane-split k: coalesced
        float4 p1 = brow[lane * 2 + 1];
        float zacc = 0.f;
        for (int jt = 0; jt < 64; ++jt) {
            int j = jt * 4 + w;            // wave w handles j % 4 == w
            const float4* wrow = (const float4*)(Ws1 + (size_t)j * DST);
            float d = dot4(wrow[lane * 2], p0) + dot4(wrow[lane * 2 + 1], p1);
            d = wave_reduce(d);
            if (lane == 0) zacc += fmaxf(d + bs1[j], 0.f) * Ws2[j];
        }
        if (lane == 0) s_zp[w] = zacc;
        __syncthreads();
        if (t == 0) imp[i] = s_zp[0] + s_zp[1] + s_zp[2] + s_zp[3] + bs2[0];
    } else {
        int idx = (blk - (64 + POOLBLKS)) * 256 + t;  // 1024*256 = 262144 float4
        ((float4*)out)[idx] = ((const float4*)bank)[idx & 8191];
    }
}

// ============ kB: per-(batch, j-chunk): in-block pool2 + h1 chunk ===========
// 128 blocks: b = blk>>2, jc = blk&3; h1[b][jc*128 .. jc*128+127]
__global__ void kB(const float* __restrict__ partial,
                   const float* __restrict__ W1, const float* __restrict__ b1,
                   float* __restrict__ h1) {
    int blk = blockIdx.x;
    int t = threadIdx.x;
    int b = blk >> 2, jc = blk & 3;
    __shared__ float4 s_pool[256];

    // stage A: reduce 32 partial chunks -> pooled_b (mean); 128 KB read
    const float4* src = (const float4*)(partial + (size_t)b * CHUNKS * DIN);
    float4 acc = make_float4(0.f, 0.f, 0.f, 0.f);
#pragma unroll 8
    for (int c = 0; c < CHUNKS; ++c) {
        float4 v = src[c * (DIN / 4) + t];
        acc.x += v.x; acc.y += v.y; acc.z += v.z; acc.w += v.w;
    }
    const float invS = 1.0f / (float)SS;
    acc.x *= invS; acc.y *= invS; acc.z *= invS; acc.w *= invS;
    s_pool[t] = acc;
    __syncthreads();

    // stage B: wave-per-j GEMV, lane-split k (coalesced W1 reads, chunk read once)
    int w = t >> 6, lane = t & 63;
    float4 p[4];
#pragma unroll
    for (int m = 0; m < 4; ++m) p[m] = s_pool[lane * 4 + m];
    for (int jt = 0; jt < 32; ++jt) {
        int j = jc * 128 + jt * 4 + w;
        const float4* wrow = (const float4*)(W1 + (size_t)j * DIN);
        float d = 0.f;
#pragma unroll
        for (int m = 0; m < 4; ++m) d += dot4(wrow[lane * 4 + m], p[m]);
        d = wave_reduce(d);
        if (lane == 0) h1[(size_t)b * DST + j] = fmaxf(d + b1[j], 0.f);
    }
}

// ============ kC: per-batch: h2 -> z -> num_states; ranks; mask row =========
// 32 blocks, one per batch
__global__ void kC(const float* __restrict__ h1,
                   const float* __restrict__ W2, const float* __restrict__ b2,
                   const float* __restrict__ W3, const float* __restrict__ b3,
                   const float* __restrict__ imp,
                   float* __restrict__ mask_out) {
    int b = blockIdx.x;
    int t = threadIdx.x;
    int w = t >> 6, lane = t & 63;
    __shared__ float s_zp[4];
    __shared__ float s_imp[NST];
    __shared__ int s_ns;

    const float4* hrow = (const float4*)(h1 + (size_t)b * DST);
    float4 h0 = hrow[lane * 2];
    float4 h1r = hrow[lane * 2 + 1];
    float zacc = 0.f;
    for (int jt = 0; jt < 64; ++jt) {
        int j = jt * 4 + w;
        const float4* wrow = (const float4*)(W2 + (size_t)j * DST);
        float d = dot4(wrow[lane * 2], h0) + dot4(wrow[lane * 2 + 1], h1r);
        d = wave_reduce(d);
        if (lane == 0) zacc += fmaxf(d + b2[j], 0.f) * W3[j];
    }
    if (lane == 0) s_zp[w] = zacc;
    if (t < NST) s_imp[t] = imp[t];
    __syncthreads();
    if (t == 0) {
        float z = s_zp[0] + s_zp[1] + s_zp[2] + s_zp[3] + b3[0];
        float cx = 1.0f / (1.0f + expf(-z));
        int ns = (int)rintf(4.0f + cx * 60.0f);   // round-half-even = jnp.round
        s_ns = min(max(ns, 4), 64);
    }
    __syncthreads();
    if (t < NST) {
        // rank in descending importance; stable argsort tie-break: lower idx wins
        float mine = s_imp[t];
        int r = 0;
        for (int j = 0; j < NST; ++j) {
            float o = s_imp[j];
            if (o > mine || (o == mine && j < t)) ++r;
        }
        mask_out[b * NST + t] = (r < s_ns) ? 1.0f : 0.0f;
    }
}

extern "C" void kernel_launch(void* const* d_in, const int* in_sizes, int n_in,
                              void* d_out, int out_size, void* d_ws, size_t ws_size,
                              hipStream_t stream) {
    const float* x    = (const float*)d_in[0];
    const float* W1   = (const float*)d_in[1];
    const float* b1   = (const float*)d_in[2];
    const float* W2   = (const float*)d_in[3];
    const float* b2   = (const float*)d_in[4];
    const float* W3   = (const float*)d_in[5];
    const float* b3   = (const float*)d_in[6];
    const float* Ws1  = (const float*)d_in[7];
    const float* bs1  = (const float*)d_in[8];
    const float* Ws2  = (const float*)d_in[9];
    const float* bs2  = (const float*)d_in[10];
    const float* bank = (const float*)d_in[11];
    // d_in[12] = temperature: unused — softmax with positive temp is monotonic,
    // so ranks of raw logits equal ranks of importance.

    float* out = (float*)d_out;
    float* mask_out = out + (size_t)BB * NST * DST;

    float* ws = (float*)d_ws;
    float* partial = ws;                                   // 1024*1024 floats (4 MB)
    float* h1  = partial + (size_t)POOLBLKS * DIN;         // 16384
    float* imp = h1 + (size_t)BB * DST;                    // 64

    kA<<<64 + POOLBLKS + 1024, 256, 0, stream>>>(x, bank, Ws1, bs1, Ws2, bs2,
                                                 partial, imp, out);
    kB<<<128, 256, 0, stream>>>(partial, W1, b1, h1);
    kC<<<32, 256, 0, stream>>>(h1, W2, b2, W3, b3, imp, mask_out);
}

// Round 8
// 107.012 us; speedup vs baseline: 1.3155x; 1.3155x over previous
//
#include <hip/hip_runtime.h>

#define BB 32
#define SS 2048
#define DIN 1024
#define DST 512
#define DH 256   // DST/2
#define NST 64   // MAX_STATES
#define SC 64                   // seq rows per pool chunk
#define CHUNKS (SS / SC)        // 32
#define POOLBLKS (BB * CHUNKS)  // 1024

__device__ __forceinline__ float dot4(float4 a, float4 b) {
    return a.x * b.x + a.y * b.y + a.z * b.z + a.w * b.w;
}

// ============ kA: pool partials [0,1024) + hs rows [1024,1088) + bcast ======
// No shuffle chains anywhere; hs is R3-k3 style (weight broadcast across
// lanes, per-thread k-loop with full ILP).
__global__ void kA(const float* __restrict__ x, const float* __restrict__ bank,
                   const float* __restrict__ Ws1, const float* __restrict__ bs1,
                   float* __restrict__ partial, float* __restrict__ hs,
                   float* __restrict__ out) {
    int blk = blockIdx.x, t = threadIdx.x;
    if (blk < POOLBLKS) {
        int b = blk >> 5;        // batch
        int c = blk & 31;        // chunk of 64 seq rows
        const float4* xp = (const float4*)(x + ((size_t)b * SS + (size_t)c * SC) * DIN);
        float4 acc = make_float4(0.f, 0.f, 0.f, 0.f);
#pragma unroll 8
        for (int s = 0; s < SC; ++s) {
            float4 v = xp[s * (DIN / 4) + t];
            acc.x += v.x; acc.y += v.y; acc.z += v.z; acc.w += v.w;
        }
        ((float4*)(partial + (size_t)blk * DIN))[t] = acc;
    } else if (blk < POOLBLKS + 64) {
        // hs[i][j] = relu(dot(bank_i, Ws1_j) + bs1_j); j = g*4 + (t>>6), i = t&63
        int g = blk - POOLBLKS;
        int i = t & 63;
        int j = g * 4 + (t >> 6);
        const float4* w = (const float4*)(Ws1 + (size_t)j * DST);  // broadcast among 64 lanes
        const float4* s = (const float4*)(bank + (size_t)i * DST);
        float a0 = 0.f, a1 = 0.f;
#pragma unroll 8
        for (int k = 0; k < DST / 4; k += 2) {
            a0 += dot4(w[k], s[k]);
            a1 += dot4(w[k + 1], s[k + 1]);
        }
        hs[(size_t)i * DH + j] = fmaxf(a0 + a1 + bs1[j], 0.f);
    } else {
        int idx = (blk - (POOLBLKS + 64)) * 256 + t;  // 1024*256 = 262144 float4
        ((float4*)out)[idx] = ((const float4*)bank)[idx & 8191];
    }
}

// ============ kB: [0,128) in-LDS pool2 + h1 chunk; block 128 = imp ==========
// h1: 2 threads per output j (k-split halves), single LDS combine, no shuffles.
// imp: thread-per-state full row dot, no shuffles.
__global__ void kB(const float* __restrict__ partial,
                   const float* __restrict__ W1, const float* __restrict__ b1,
                   const float* __restrict__ hs,
                   const float* __restrict__ Ws2, const float* __restrict__ bs2,
                   float* __restrict__ h1, float* __restrict__ imp) {
    int blk = blockIdx.x, t = threadIdx.x;
    if (blk < 128) {
        int b = blk >> 2, jc = blk & 3;
        __shared__ float4 s_pool[256];   // pooled_b (1024 floats)
        __shared__ float s_a[128], s_b[128];

        // stage A: reduce 32 partial chunks -> pooled_b (mean), into LDS
        const float4* src = (const float4*)(partial + (size_t)b * CHUNKS * DIN);
        float4 acc = make_float4(0.f, 0.f, 0.f, 0.f);
#pragma unroll 8
        for (int c = 0; c < CHUNKS; ++c) {
            float4 v = src[c * (DIN / 4) + t];
            acc.x += v.x; acc.y += v.y; acc.z += v.z; acc.w += v.w;
        }
        const float invS = 1.0f / (float)SS;
        acc.x *= invS; acc.y *= invS; acc.z *= invS; acc.w *= invS;
        s_pool[t] = acc;
        __syncthreads();

        // stage B: h1 rows jc*128..+127; thread (jj, half) dots 512 elems
        int jj = t & 127, half = t >> 7;
        int j = jc * 128 + jj;
        const float4* w = (const float4*)(W1 + (size_t)j * DIN) + half * 128;
        const float4* p = s_pool + half * 128;
        float d0 = 0.f, d1 = 0.f;
#pragma unroll 8
        for (int k = 0; k < 128; k += 2) {
            d0 += dot4(w[k], p[k]);
            d1 += dot4(w[k + 1], p[k + 1]);
        }
        if (half == 0) s_a[jj] = d0 + d1; else s_b[jj] = d0 + d1;
        __syncthreads();
        if (t < 128) {
            int jg = jc * 128 + t;
            h1[(size_t)b * DST + jg] = fmaxf(s_a[t] + s_b[t] + b1[jg], 0.f);
        }
    } else if (t < NST) {
        // imp[i] = dot(hs_i, Ws2) + bs2; thread-per-state, Ws2 broadcast
        const float4* hv = (const float4*)(hs + (size_t)t * DH);
        const float4* w  = (const float4*)(Ws2);
        float a = 0.f;
#pragma unroll 8
        for (int k = 0; k < DH / 4; ++k) a += dot4(hv[k], w[k]);
        imp[t] = a + bs2[0];
    }
}

// ============ kC: per-batch: h2 (thread-per-j) -> z -> ns; ranks; mask ======
// One LDS fold + ONE 6-shfl reduce per block total.
__global__ void kC(const float* __restrict__ h1,
                   const float* __restrict__ W2, const float* __restrict__ b2,
                   const float* __restrict__ W3, const float* __restrict__ b3,
                   const float* __restrict__ imp, float* __restrict__ mask_out) {
    int b = blockIdx.x, t = threadIdx.x;
    __shared__ float4 s_h[128];     // h1_b (512 floats)
    __shared__ float s_c[DH];       // h2_j * W3_j
    __shared__ float s_imp[NST];
    __shared__ int s_ns;

    if (t < 128) s_h[t] = ((const float4*)(h1 + (size_t)b * DST))[t];
    if (t >= 128 && t < 192) s_imp[t - 128] = imp[t - 128];
    __syncthreads();

    // h2_j: j = t, each thread reads its own W2 row (L2-hot), h1 from LDS
    {
        const float4* w = (const float4*)(W2 + (size_t)t * DST);
        float a0 = 0.f, a1 = 0.f;
#pragma unroll 8
        for (int k = 0; k < 128; k += 2) {
            a0 += dot4(w[k], s_h[k]);
            a1 += dot4(w[k + 1], s_h[k + 1]);
        }
        float h2v = fmaxf(a0 + a1 + b2[t], 0.f);
        s_c[t] = h2v * W3[t];
    }
    __syncthreads();

    if (t < 64) {
        float zp = s_c[t] + s_c[t + 64] + s_c[t + 128] + s_c[t + 192];
        zp += __shfl_xor(zp, 1);
        zp += __shfl_xor(zp, 2);
        zp += __shfl_xor(zp, 4);
        zp += __shfl_xor(zp, 8);
        zp += __shfl_xor(zp, 16);
        zp += __shfl_xor(zp, 32);
        if (t == 0) {
            float z = zp + b3[0];
            float cx = 1.0f / (1.0f + expf(-z));
            int ns = (int)rintf(4.0f + cx * 60.0f);   // round-half-even = jnp.round
            s_ns = min(max(ns, 4), 64);
        }
    }
    __syncthreads();

    if (t < 64) {
        // rank in descending importance; stable argsort tie-break: lower idx wins
        float mine = s_imp[t];
        int r = 0;
        for (int j2 = 0; j2 < 64; ++j2) {
            float o = s_imp[j2];   // same addr all lanes -> LDS broadcast
            if (o > mine || (o == mine && j2 < t)) ++r;
        }
        mask_out[b * NST + t] = (r < s_ns) ? 1.0f : 0.0f;
    }
}

extern "C" void kernel_launch(void* const* d_in, const int* in_sizes, int n_in,
                              void* d_out, int out_size, void* d_ws, size_t ws_size,
                              hipStream_t stream) {
    const float* x    = (const float*)d_in[0];
    const float* W1   = (const float*)d_in[1];
    const float* b1   = (const float*)d_in[2];
    const float* W2   = (const float*)d_in[3];
    const float* b2   = (const float*)d_in[4];
    const float* W3   = (const float*)d_in[5];
    const float* b3   = (const float*)d_in[6];
    const float* Ws1  = (const float*)d_in[7];
    const float* bs1  = (const float*)d_in[8];
    const float* Ws2  = (const float*)d_in[9];
    const float* bs2  = (const float*)d_in[10];
    const float* bank = (const float*)d_in[11];
    // d_in[12] = temperature: unused — softmax with positive temp is monotonic,
    // so ranks of raw logits equal ranks of importance.

    float* out = (float*)d_out;
    float* mask_out = out + (size_t)BB * NST * DST;

    float* ws = (float*)d_ws;
    float* partial = ws;                                   // 1024*1024 floats (4 MB)
    float* hs  = partial + (size_t)POOLBLKS * DIN;         // 64*256
    float* h1  = hs + (size_t)NST * DH;                    // 32*512
    float* imp = h1 + (size_t)BB * DST;                    // 64

    kA<<<POOLBLKS + 64 + 1024, 256, 0, stream>>>(x, bank, Ws1, bs1, partial, hs, out);
    kB<<<129, 256, 0, stream>>>(partial, W1, b1, hs, Ws2, bs2, h1, imp);
    kC<<<32, 256, 0, stream>>>(h1, W2, b2, W3, b3, imp, mask_out);
}